// Round 3
// baseline (94609.119 us; speedup 1.0000x reference)
//
#include <hip/hip_runtime.h>
#include <math.h>

// ReEig via matrix-sign iteration (accelerated equioscillating-cubic schedule):
//   f(X) = 0.5*(X + eps*I + (X - eps*I) * sign(X - eps*I))
// Y <- a_k*Y - b_k*Y^3, coefficients mapping [l,1]->[l',1], l' ~ 2.598*l.
// All heavy compute = fp32 vector-ALU GEMMs (no fp32 MFMA on CDNA4).

#define N 4096
#define NN ((size_t)N * (size_t)N)
#define EPS 1e-5f
#define NITER 26

// ---------------- Frobenius norm^2 reduction ----------------
__global__ void fro_kernel(const float* __restrict__ X, float* __restrict__ scal) {
    __shared__ float red[4];
    int tid = threadIdx.x;
    size_t gid = (size_t)blockIdx.x * blockDim.x + tid;
    size_t stride = (size_t)gridDim.x * blockDim.x;
    const float4* X4 = (const float4*)X;
    size_t n4 = NN / 4;
    float s = 0.f;
    for (size_t i = gid; i < n4; i += stride) {
        float4 v = X4[i];
        s += v.x * v.x + v.y * v.y + v.z * v.z + v.w * v.w;
    }
    #pragma unroll
    for (int o = 32; o > 0; o >>= 1) s += __shfl_down(s, o, 64);
    int lane = tid & 63, wv = tid >> 6;
    if (lane == 0) red[wv] = s;
    __syncthreads();
    if (tid == 0) atomicAdd(&scal[0], red[0] + red[1] + red[2] + red[3]);
}

// ---------------- schedule: c = ||X||_F, coefficients (a_k, b_k) ----------------
// scal layout: [0]=fro2, [1]=c, [2+2k]=a_k, [3+2k]=b_k
__global__ void schedule_kernel(float* __restrict__ scal) {
    if (threadIdx.x != 0 || blockIdx.x != 0) return;
    double c = sqrt((double)scal[0]);
    scal[1] = (float)c;
    double l = 1e-5 / c;                    // conservative lower edge of |spec(Y0)|
    const double KC = 2.598076211353316;    // 3*sqrt(3)/2
    for (int k = 0; k < NITER; ++k) {
        double s = 1.0 + l + l * l;
        double b = KC / (s * sqrt(s));
        double a = b * s;
        scal[2 + 2 * k] = (float)a;
        scal[3 + 2 * k] = (float)b;
        l = b * (s - 1.0);                  // = p(l) = p(1), new lower edge
        if (l > 1.0) l = 1.0;
    }
}

// ---------------- Y0 = (X - eps*I) / c ----------------
__global__ void init_kernel(const float* __restrict__ X, float* __restrict__ Y,
                            const float* __restrict__ scal) {
    float inv_c = 1.0f / scal[1];
    size_t gid = (size_t)blockIdx.x * blockDim.x + threadIdx.x;
    size_t stride = (size_t)gridDim.x * blockDim.x;
    const float4* X4 = (const float4*)X;
    float4* Y4 = (float4*)Y;
    size_t n4 = NN / 4;
    for (size_t i = gid; i < n4; i += stride) {
        float4 v = X4[i];
        size_t base = i * 4;
        int row = (int)(base >> 12);        // / 4096
        int col = (int)(base & 4095);
        int d = row - col;                  // diagonal element at slot d if 0<=d<4
        if (d >= 0 && d < 4) (&v.x)[d] -= EPS;
        v.x *= inv_c; v.y *= inv_c; v.z *= inv_c; v.w *= inv_c;
        Y4[i] = v;
    }
}

// ---------------- GEMM: D = op(A)*B with fused epilogues ----------------
// asub: if 1, A is read as (A - eps*I)  (used for final (X-eps*I)*S)
// mode 0: D = acc                         (T = Y*Y)
// mode 1: D = a*E - b*acc    (E = Y)      (Y' = a*Y - b*Y*T)
// mode 2: D = 0.5*E + 0.5*acc + 0.5*eps*I (E = X, final reconstruction)
__launch_bounds__(256)
__global__ void gemm_kernel(const float* __restrict__ A, const float* __restrict__ B,
                            float* __restrict__ D, const float* __restrict__ E,
                            const float* __restrict__ scal, int k, int mode, int asub) {
    __shared__ float As[16][132];   // As[k][m] (A tile transposed on store)
    __shared__ float Bs[16][132];   // Bs[k][n]
    int tid = threadIdx.x;
    int lane = tid & 63;
    int wv = tid >> 6;
    int lx = lane & 7, ly = (lane >> 3) & 7;   // 8x8 lanes within wave
    int wx = wv & 1, wy = wv >> 1;             // 2x2 waves
    int bx = blockIdx.x, by = blockIdx.y;
    int row0 = by * 128 + wy * 64 + ly * 8;
    int col0 = bx * 128 + wx * 64 + lx * 8;

    float acc[8][8];
    #pragma unroll
    for (int i = 0; i < 8; ++i)
        #pragma unroll
        for (int j = 0; j < 8; ++j) acc[i][j] = 0.f;

    for (int kt = 0; kt < N; kt += 16) {
        #pragma unroll
        for (int h = 0; h < 2; ++h) {
            int q = tid + h * 256;
            // A tile: 128 rows x 16 k, transpose on store
            int ra = q >> 2, ca = q & 3;
            int grow = by * 128 + ra;
            float4 va = *(const float4*)&A[(size_t)grow * N + kt + ca * 4];
            if (asub) {
                int d = grow - (kt + ca * 4);
                if (d >= 0 && d < 4) (&va.x)[d] -= EPS;
            }
            As[ca * 4 + 0][ra] = va.x;
            As[ca * 4 + 1][ra] = va.y;
            As[ca * 4 + 2][ra] = va.z;
            As[ca * 4 + 3][ra] = va.w;
            // B tile: 16 k x 128 cols, direct
            int rb = q >> 5, cb = q & 31;
            float4 vb = *(const float4*)&B[(size_t)(kt + rb) * N + bx * 128 + cb * 4];
            *(float4*)&Bs[rb][cb * 4] = vb;
        }
        __syncthreads();
        #pragma unroll
        for (int kk = 0; kk < 16; ++kk) {
            float4 a0 = *(const float4*)&As[kk][wy * 64 + ly * 8];
            float4 a1 = *(const float4*)&As[kk][wy * 64 + ly * 8 + 4];
            float4 b0 = *(const float4*)&Bs[kk][wx * 64 + lx * 8];
            float4 b1 = *(const float4*)&Bs[kk][wx * 64 + lx * 8 + 4];
            float av[8] = {a0.x, a0.y, a0.z, a0.w, a1.x, a1.y, a1.z, a1.w};
            float bv[8] = {b0.x, b0.y, b0.z, b0.w, b1.x, b1.y, b1.z, b1.w};
            #pragma unroll
            for (int i = 0; i < 8; ++i)
                #pragma unroll
                for (int j = 0; j < 8; ++j)
                    acc[i][j] = fmaf(av[i], bv[j], acc[i][j]);
        }
        __syncthreads();
    }

    float aa = 0.f, bb = 0.f;
    if (mode == 1) { aa = scal[2 + 2 * k]; bb = scal[3 + 2 * k]; }

    #pragma unroll
    for (int i = 0; i < 8; ++i) {
        int row = row0 + i;
        size_t off = (size_t)row * N + col0;
        float4 o0, o1;
        if (mode == 0) {
            o0 = make_float4(acc[i][0], acc[i][1], acc[i][2], acc[i][3]);
            o1 = make_float4(acc[i][4], acc[i][5], acc[i][6], acc[i][7]);
        } else if (mode == 1) {
            float4 e0 = *(const float4*)&E[off];
            float4 e1 = *(const float4*)&E[off + 4];
            o0 = make_float4(aa * e0.x - bb * acc[i][0], aa * e0.y - bb * acc[i][1],
                             aa * e0.z - bb * acc[i][2], aa * e0.w - bb * acc[i][3]);
            o1 = make_float4(aa * e1.x - bb * acc[i][4], aa * e1.y - bb * acc[i][5],
                             aa * e1.z - bb * acc[i][6], aa * e1.w - bb * acc[i][7]);
        } else {
            float4 e0 = *(const float4*)&E[off];
            float4 e1 = *(const float4*)&E[off + 4];
            float r[8];
            #pragma unroll
            for (int j = 0; j < 8; ++j) {
                float e = (j < 4) ? (&e0.x)[j] : (&e1.x)[j - 4];
                r[j] = 0.5f * e + 0.5f * acc[i][j];
                if (col0 + j == row) r[j] += 0.5f * EPS;
            }
            o0 = make_float4(r[0], r[1], r[2], r[3]);
            o1 = make_float4(r[4], r[5], r[6], r[7]);
        }
        *(float4*)&D[off] = o0;
        *(float4*)&D[off + 4] = o1;
    }
}

extern "C" void kernel_launch(void* const* d_in, const int* in_sizes, int n_in,
                              void* d_out, int out_size, void* d_ws, size_t ws_size,
                              hipStream_t stream) {
    const float* X = (const float*)d_in[0];
    float* out = (float*)d_out;
    float* ws0 = (float*)d_ws;
    float* ws1 = ws0 + NN;
    float* scal = ws1 + NN;             // scalars: fro2, c, (a_k,b_k)...

    hipMemsetAsync(scal, 0, 256 * sizeof(float), stream);
    fro_kernel<<<2048, 256, 0, stream>>>(X, scal);
    schedule_kernel<<<1, 64, 0, stream>>>(scal);
    init_kernel<<<2048, 256, 0, stream>>>(X, ws0, scal);

    // 3-buffer rotation: iter uses Y@buf[p], T@buf[(p+1)%3], Ynext@buf[(p+2)%3]
    float* buf[3] = {ws0, ws1, out};
    dim3 grid(N / 128, N / 128), blk(256);
    int p = 0;
    for (int k = 0; k < NITER; ++k) {
        float* Y  = buf[p];
        float* T  = buf[(p + 1) % 3];
        float* Yn = buf[(p + 2) % 3];
        gemm_kernel<<<grid, blk, 0, stream>>>(Y, Y, T, nullptr, scal, 0, 0, 0);   // T = Y*Y
        gemm_kernel<<<grid, blk, 0, stream>>>(Y, T, Yn, Y, scal, k, 1, 0);        // Y' = aY - b*Y*T
        p = (p + 2) % 3;
    }
    // After 26 iters p=1 -> S in ws1. out = 0.5*X + 0.5*eps*I + 0.5*(X-eps*I)*S
    gemm_kernel<<<grid, blk, 0, stream>>>(X, buf[p], out, X, scal, 0, 2, 1);
}

// Round 8
// 94489.508 us; speedup vs baseline: 1.0013x; 1.0013x over previous
//
#include <hip/hip_runtime.h>
#include <math.h>

// ReEig via matrix-sign iteration. DIAGNOSTIC v2 (explosion-proof bisect):
// HEAD = 2 bf16x3-split MFMA iterations (4 gemm3 calls), then sanitize
// (nonfinite->0, clamp +-2) and FULL RESTART: fresh Frobenius normalization
// + fresh 26-step fp32 schedule computing S = sign(Y2~). Sign idempotency
// => correct if head correct; ||Y~||_F <= 1 => spectral <= 1 => tail CANNOT
// explode even on garbage head output (fixes round-7's sanitizer hole).
// Decode: PASS = gemm3 value-correct; FAIL-finite = gemm3 wrong in <=2
// iters; FAIL-NaN = gemm3 emits NaN from clean bounded input (OOB).

#define N 4096
#define NN ((size_t)N * (size_t)N)
#define EPS 1e-5f
#define NITER 26
#define LDSROW 80
#define LDSTILE (128 * LDSROW)

typedef unsigned short u16;
typedef unsigned int u32;
typedef __attribute__((ext_vector_type(8))) short bf16x8;
typedef __attribute__((ext_vector_type(4))) float f32x4;

__device__ __forceinline__ float bf2f(u16 h) {
    union { u32 u; float f; } c; c.u = ((u32)h) << 16; return c.f;
}
__device__ __forceinline__ u16 f2bf(float f) {
    union { float f; u32 u; } c; c.f = f;
    return (u16)((c.u + 0x7FFFu + ((c.u >> 16) & 1u)) >> 16);  // RNE
}

// ---------------- Frobenius norm^2 reduction ----------------
__global__ void fro_kernel(const float* __restrict__ X, float* __restrict__ scal) {
    __shared__ float red[4];
    int tid = threadIdx.x;
    size_t gid = (size_t)blockIdx.x * blockDim.x + tid;
    size_t stride = (size_t)gridDim.x * blockDim.x;
    const float4* X4 = (const float4*)X;
    size_t n4 = NN / 4;
    float s = 0.f;
    for (size_t i = gid; i < n4; i += stride) {
        float4 v = X4[i];
        s += v.x * v.x + v.y * v.y + v.z * v.z + v.w * v.w;
    }
    #pragma unroll
    for (int o = 32; o > 0; o >>= 1) s += __shfl_down(s, o, 64);
    int lane = tid & 63, wv = tid >> 6;
    if (lane == 0) red[wv] = s;
    __syncthreads();
    if (tid == 0) atomicAdd(&scal[0], red[0] + red[1] + red[2] + red[3]);
}

// scal: [0]=fro2(X) [1]=c [2..53]=(a,b) head pairs
//       [60]=fro2(clean Y2) [61]=inv_ctilde [62]=ctilde [64..115]=(a,b) tail pairs
__global__ void schedule_kernel(float* __restrict__ scal) {
    if (threadIdx.x != 0 || blockIdx.x != 0) return;
    double c = sqrt((double)scal[0]);
    scal[1] = (float)c;
    double l = 1e-5 / c;
    const double KC = 2.598076211353316;    // 3*sqrt(3)/2
    for (int k = 0; k < NITER; ++k) {
        double s = 1.0 + l + l * l;
        double b = KC / (s * sqrt(s));
        double a = b * s;
        scal[2 + 2 * k] = (float)a;
        scal[3 + 2 * k] = (float)b;
        l = b * (s - 1.0);
        if (l > 1.0) l = 1.0;
    }
}

// fresh restart schedule from fro2 of sanitized head output
__global__ void schedule2_kernel(float* __restrict__ scal) {
    if (threadIdx.x != 0 || blockIdx.x != 0) return;
    double c = sqrt((double)scal[60]);
    float inv = (c > 1e-20) ? (float)(1.0 / c) : 0.f;
    scal[61] = inv;
    scal[62] = (float)c;
    double l = (c > 1e-20) ? (1e-5 / c) : 1e-3;
    const double KC = 2.598076211353316;
    for (int k = 0; k < NITER; ++k) {
        double s = 1.0 + l + l * l;
        double b = KC / (s * sqrt(s));
        double a = b * s;
        scal[64 + 2 * k] = (float)a;
        scal[65 + 2 * k] = (float)b;
        l = b * (s - 1.0);
        if (l > 1.0) l = 1.0;
    }
}

// ---------------- Y0 = (X - eps*I)/c  as split bf16 pair ----------------
__global__ void init_split_kernel(const float* __restrict__ X, u16* __restrict__ Hi,
                                  u16* __restrict__ Lo, const float* __restrict__ scal) {
    float inv_c = 1.0f / scal[1];
    size_t gid = (size_t)blockIdx.x * blockDim.x + threadIdx.x;
    size_t stride = (size_t)gridDim.x * blockDim.x;
    const float4* X4 = (const float4*)X;
    size_t n4 = NN / 4;
    for (size_t i = gid; i < n4; i += stride) {
        float4 v = X4[i];
        size_t base = i * 4;
        int row = (int)(base >> 12);
        int col = (int)(base & 4095);
        int d = row - col;
        if (d >= 0 && d < 4) (&v.x)[d] -= EPS;
        u16 h[4], l[4];
        #pragma unroll
        for (int j = 0; j < 4; ++j) {
            float y = (&v.x)[j] * inv_c;
            h[j] = f2bf(y);
            l[j] = f2bf(y - bf2f(h[j]));
        }
        *(ushort4*)&Hi[base] = make_ushort4(h[0], h[1], h[2], h[3]);
        *(ushort4*)&Lo[base] = make_ushort4(l[0], l[1], l[2], l[3]);
    }
}

// ---------------- sanitize: split pair -> bounded fp32 ----------------
__device__ __forceinline__ float cleanv(u16 h, u16 l) {
    float v = bf2f(h) + bf2f(l);
    if (!isfinite(v)) v = 0.f;
    return fminf(2.0f, fmaxf(-2.0f, v));
}
__global__ void san_pass1(const u16* __restrict__ Yh, const u16* __restrict__ Yl,
                          float* __restrict__ scal) {
    __shared__ float red[4];
    int tid = threadIdx.x;
    size_t gid = (size_t)blockIdx.x * blockDim.x + tid;
    size_t stride = (size_t)gridDim.x * blockDim.x;
    float s = 0.f;
    size_t n4 = NN / 4;
    for (size_t i = gid; i < n4; i += stride) {
        size_t base = i * 4;
        ushort4 h = *(const ushort4*)&Yh[base];
        ushort4 l = *(const ushort4*)&Yl[base];
        float v0 = cleanv(h.x, l.x), v1 = cleanv(h.y, l.y);
        float v2 = cleanv(h.z, l.z), v3 = cleanv(h.w, l.w);
        s += v0 * v0 + v1 * v1 + v2 * v2 + v3 * v3;
    }
    #pragma unroll
    for (int o = 32; o > 0; o >>= 1) s += __shfl_down(s, o, 64);
    int lane = tid & 63, wv = tid >> 6;
    if (lane == 0) red[wv] = s;
    __syncthreads();
    if (tid == 0) atomicAdd(&scal[60], red[0] + red[1] + red[2] + red[3]);
}
__global__ void san_pass2(const u16* __restrict__ Yh, const u16* __restrict__ Yl,
                          float* __restrict__ F, const float* __restrict__ scal) {
    float sc = scal[61];   // 1/ctilde (0 if degenerate)
    size_t gid = (size_t)blockIdx.x * blockDim.x + threadIdx.x;
    size_t stride = (size_t)gridDim.x * blockDim.x;
    size_t n4 = NN / 4;
    for (size_t i = gid; i < n4; i += stride) {
        size_t base = i * 4;
        ushort4 h = *(const ushort4*)&Yh[base];
        ushort4 l = *(const ushort4*)&Yl[base];
        float4 o;
        o.x = cleanv(h.x, l.x) * sc;
        o.y = cleanv(h.y, l.y) * sc;
        o.z = cleanv(h.z, l.z) * sc;
        o.w = cleanv(h.w, l.w) * sc;
        *(float4*)&F[base] = o;
    }
}

// ---------------- split-bf16 x3 MFMA GEMM (under test) ----------------
__launch_bounds__(256)
__global__ void gemm3_kernel(const u16* __restrict__ Ah, const u16* __restrict__ Al,
                             const u16* __restrict__ Bh, const u16* __restrict__ Bl,
                             const u16* __restrict__ Eh, const u16* __restrict__ El,
                             const float* __restrict__ Xf, float* __restrict__ Dout,
                             u16* __restrict__ Dh, u16* __restrict__ Dl,
                             const float* __restrict__ scal, int kidx, int mode) {
    __shared__ __align__(16) char smem[4 * LDSTILE];
    int tid = threadIdx.x;
    int lane = tid & 63;
    int wv = tid >> 6;
    int wr = wv >> 1, wc = wv & 1;
    int bx = blockIdx.x, by = blockIdx.y;

    int rs = tid >> 2;
    int qs = tid & 3;
    const u16* gptr[4][2];
    char* lptr[4][2];
    {
        const u16* bases[4] = {Ah, Al, Bh, Bl};
        #pragma unroll
        for (int t = 0; t < 4; ++t) {
            int row0 = (t < 2) ? by * 128 : bx * 128;
            #pragma unroll
            for (int h = 0; h < 2; ++h) {
                int r = rs + h * 64;
                gptr[t][h] = bases[t] + (size_t)(row0 + r) * N + qs * 8;
                lptr[t][h] = smem + t * LDSTILE + r * LDSROW + qs * 16;
            }
        }
    }

    int q = lane >> 4;
    u32 aoff[4], boff[4];
    #pragma unroll
    for (int m = 0; m < 4; ++m) {
        int rf = wr * 64 + m * 16 + (lane & 15);
        aoff[m] = (u32)(rf * LDSROW + q * 16);
        int rg = wc * 64 + m * 16 + (lane & 15);
        boff[m] = (u32)(rg * LDSROW + q * 16);
    }

    f32x4 acc[4][4];
    #pragma unroll
    for (int m = 0; m < 4; ++m)
        #pragma unroll
        for (int n = 0; n < 4; ++n) acc[m][n] = (f32x4){0.f, 0.f, 0.f, 0.f};

    for (int kt = 0; kt < N; kt += 32) {
        float4 stg[4][2];
        #pragma unroll
        for (int t = 0; t < 4; ++t)
            #pragma unroll
            for (int h = 0; h < 2; ++h) {
                stg[t][h] = *(const float4*)gptr[t][h];
                gptr[t][h] += 32;
            }
        __syncthreads();
        #pragma unroll
        for (int t = 0; t < 4; ++t)
            #pragma unroll
            for (int h = 0; h < 2; ++h)
                *(float4*)lptr[t][h] = stg[t][h];
        __syncthreads();

        bf16x8 fah[4], fal[4], fbh[4], fbl[4];
        #pragma unroll
        for (int m = 0; m < 4; ++m) {
            fah[m] = *(const bf16x8*)(smem + aoff[m]);
            fal[m] = *(const bf16x8*)(smem + LDSTILE + aoff[m]);
            fbh[m] = *(const bf16x8*)(smem + 2 * LDSTILE + boff[m]);
            fbl[m] = *(const bf16x8*)(smem + 3 * LDSTILE + boff[m]);
        }
        #pragma unroll
        for (int m = 0; m < 4; ++m)
            #pragma unroll
            for (int n = 0; n < 4; ++n) {
                acc[m][n] = __builtin_amdgcn_mfma_f32_16x16x32_bf16(fah[m], fbh[n], acc[m][n], 0, 0, 0);
                acc[m][n] = __builtin_amdgcn_mfma_f32_16x16x32_bf16(fah[m], fbl[n], acc[m][n], 0, 0, 0);
                acc[m][n] = __builtin_amdgcn_mfma_f32_16x16x32_bf16(fal[m], fbh[n], acc[m][n], 0, 0, 0);
            }
    }

    float ca = 0.f, cb = 0.f, hc = 0.f;
    if (mode == 1) { ca = scal[2 + 2 * kidx]; cb = scal[3 + 2 * kidx]; }
    if (mode == 2) { hc = 0.5f * scal[1]; }

    #pragma unroll
    for (int m = 0; m < 4; ++m) {
        #pragma unroll
        for (int n = 0; n < 4; ++n) {
            #pragma unroll
            for (int r = 0; r < 4; ++r) {
                int grow = by * 128 + wr * 64 + m * 16 + (lane >> 4) * 4 + r;
                int gcol = bx * 128 + wc * 64 + n * 16 + (lane & 15);
                size_t idx = (size_t)grow * N + gcol;
                float v = acc[m][n][r];
                if (mode == 0) {
                    u16 h = f2bf(v);
                    Dh[idx] = h;
                    Dl[idx] = f2bf(v - bf2f(h));
                } else if (mode == 1) {
                    float e = bf2f(Eh[idx]) + bf2f(El[idx]);
                    float o = ca * e - cb * v;
                    u16 h = f2bf(o);
                    Dh[idx] = h;
                    Dl[idx] = f2bf(o - bf2f(h));
                } else {
                    float o = 0.5f * Xf[idx] + hc * v;
                    if (grow == gcol) o += 0.5f * EPS;
                    Dout[idx] = o;
                }
            }
        }
    }
}

// ================= proven fp32 path (round 3) =================
__global__ void init_kernel(const float* __restrict__ X, float* __restrict__ Y,
                            const float* __restrict__ scal) {
    float inv_c = 1.0f / scal[1];
    size_t gid = (size_t)blockIdx.x * blockDim.x + threadIdx.x;
    size_t stride = (size_t)gridDim.x * blockDim.x;
    const float4* X4 = (const float4*)X;
    float4* Y4 = (float4*)Y;
    size_t n4 = NN / 4;
    for (size_t i = gid; i < n4; i += stride) {
        float4 v = X4[i];
        size_t base = i * 4;
        int row = (int)(base >> 12);
        int col = (int)(base & 4095);
        int d = row - col;
        if (d >= 0 && d < 4) (&v.x)[d] -= EPS;
        v.x *= inv_c; v.y *= inv_c; v.z *= inv_c; v.w *= inv_c;
        Y4[i] = v;
    }
}

__launch_bounds__(256)
__global__ void gemm_kernel(const float* __restrict__ A, const float* __restrict__ B,
                            float* __restrict__ D, const float* __restrict__ E,
                            const float* __restrict__ scal, int k, int mode, int asub) {
    __shared__ float As[16][132];
    __shared__ float Bs[16][132];
    int tid = threadIdx.x;
    int lane = tid & 63;
    int wv = tid >> 6;
    int lx = lane & 7, ly = (lane >> 3) & 7;
    int wx = wv & 1, wy = wv >> 1;
    int bx = blockIdx.x, by = blockIdx.y;
    int row0 = by * 128 + wy * 64 + ly * 8;
    int col0 = bx * 128 + wx * 64 + lx * 8;

    float acc[8][8];
    #pragma unroll
    for (int i = 0; i < 8; ++i)
        #pragma unroll
        for (int j = 0; j < 8; ++j) acc[i][j] = 0.f;

    for (int kt = 0; kt < N; kt += 16) {
        #pragma unroll
        for (int h = 0; h < 2; ++h) {
            int qq = tid + h * 256;
            int ra = qq >> 2, caa = qq & 3;
            int grow = by * 128 + ra;
            float4 va = *(const float4*)&A[(size_t)grow * N + kt + caa * 4];
            if (asub) {
                int d = grow - (kt + caa * 4);
                if (d >= 0 && d < 4) (&va.x)[d] -= EPS;
            }
            As[caa * 4 + 0][ra] = va.x;
            As[caa * 4 + 1][ra] = va.y;
            As[caa * 4 + 2][ra] = va.z;
            As[caa * 4 + 3][ra] = va.w;
            int rb = qq >> 5, cb = qq & 31;
            float4 vb = *(const float4*)&B[(size_t)(kt + rb) * N + bx * 128 + cb * 4];
            *(float4*)&Bs[rb][cb * 4] = vb;
        }
        __syncthreads();
        #pragma unroll
        for (int kk = 0; kk < 16; ++kk) {
            float4 a0 = *(const float4*)&As[kk][wy * 64 + ly * 8];
            float4 a1 = *(const float4*)&As[kk][wy * 64 + ly * 8 + 4];
            float4 b0 = *(const float4*)&Bs[kk][wx * 64 + lx * 8];
            float4 b1 = *(const float4*)&Bs[kk][wx * 64 + lx * 8 + 4];
            float av[8] = {a0.x, a0.y, a0.z, a0.w, a1.x, a1.y, a1.z, a1.w};
            float bv[8] = {b0.x, b0.y, b0.z, b0.w, b1.x, b1.y, b1.z, b1.w};
            #pragma unroll
            for (int i = 0; i < 8; ++i)
                #pragma unroll
                for (int j = 0; j < 8; ++j)
                    acc[i][j] = fmaf(av[i], bv[j], acc[i][j]);
        }
        __syncthreads();
    }

    float aa = 0.f, bb = 0.f;
    if (mode == 1) { aa = scal[2 + 2 * k]; bb = scal[3 + 2 * k]; }

    #pragma unroll
    for (int i = 0; i < 8; ++i) {
        int row = row0 + i;
        size_t off = (size_t)row * N + col0;
        float4 o0, o1;
        if (mode == 0) {
            o0 = make_float4(acc[i][0], acc[i][1], acc[i][2], acc[i][3]);
            o1 = make_float4(acc[i][4], acc[i][5], acc[i][6], acc[i][7]);
        } else if (mode == 1) {
            float4 e0 = *(const float4*)&E[off];
            float4 e1 = *(const float4*)&E[off + 4];
            o0 = make_float4(aa * e0.x - bb * acc[i][0], aa * e0.y - bb * acc[i][1],
                             aa * e0.z - bb * acc[i][2], aa * e0.w - bb * acc[i][3]);
            o1 = make_float4(aa * e1.x - bb * acc[i][4], aa * e1.y - bb * acc[i][5],
                             aa * e1.z - bb * acc[i][6], aa * e1.w - bb * acc[i][7]);
        } else {
            float4 e0 = *(const float4*)&E[off];
            float4 e1 = *(const float4*)&E[off + 4];
            float r[8];
            #pragma unroll
            for (int j = 0; j < 8; ++j) {
                float e = (j < 4) ? (&e0.x)[j] : (&e1.x)[j - 4];
                r[j] = 0.5f * e + 0.5f * acc[i][j];
                if (col0 + j == row) r[j] += 0.5f * EPS;
            }
            o0 = make_float4(r[0], r[1], r[2], r[3]);
            o1 = make_float4(r[4], r[5], r[6], r[7]);
        }
        *(float4*)&D[off] = o0;
        *(float4*)&D[off + 4] = o1;
    }
}

extern "C" void kernel_launch(void* const* d_in, const int* in_sizes, int n_in,
                              void* d_out, int out_size, void* d_ws, size_t ws_size,
                              hipStream_t stream) {
    const float* X = (const float*)d_in[0];
    float* out = (float*)d_out;
    dim3 grid(N / 128, N / 128), blk(256);

    size_t need_split = 1024 + 12 * NN;   // bytes
    if (ws_size >= need_split) {
        float* scal = (float*)d_ws;
        u16* b16 = (u16*)((char*)d_ws + 1024);
        u16* Y0h = b16;                      // bytes [0, 2NN)
        u16* Y0l = b16 + NN;                 // [2NN, 4NN)
        u16* Ph[3] = {b16 + 2 * NN, b16 + 4 * NN, (u16*)d_out};
        u16* Pl[3] = {b16 + 3 * NN, b16 + 5 * NN, (u16*)d_out + NN};
        // fp32 tail buffers overlay regions dead after their producers:
        float* f0 = (float*)b16;             // bytes [0, 4NN)  (over Y0 pair)
        float* f1 = (float*)(b16 + 2 * NN);  // bytes [4NN, 8NN) (over P0 pair)

        hipMemsetAsync(scal, 0, 256 * sizeof(float), stream);
        fro_kernel<<<2048, 256, 0, stream>>>(X, scal);
        schedule_kernel<<<1, 64, 0, stream>>>(scal);
        init_split_kernel<<<2048, 256, 0, stream>>>(X, Y0h, Y0l, scal);

        // ---- HEAD: 2 bf16x3 iterations (4 gemm3 calls) ----
        // T0 = Y0^2 -> P0
        gemm3_kernel<<<grid, blk, 0, stream>>>(Y0h, Y0l, Y0h, Y0l, Y0h, Y0l, X, out,
                                               Ph[0], Pl[0], scal, 0, 0);
        // Y1 = a0*Y0 - b0*Y0*T0 -> P1
        gemm3_kernel<<<grid, blk, 0, stream>>>(Y0h, Y0l, Ph[0], Pl[0], Y0h, Y0l, X, out,
                                               Ph[1], Pl[1], scal, 0, 1);
        // T1 = Y1^2 -> P2 (d_out scratch)
        gemm3_kernel<<<grid, blk, 0, stream>>>(Ph[1], Pl[1], Ph[1], Pl[1], Ph[1], Pl[1],
                                               X, out, Ph[2], Pl[2], scal, 0, 0);
        // Y2 = a1*Y1 - b1*Y1*T1 -> P0 (T0 dead)
        gemm3_kernel<<<grid, blk, 0, stream>>>(Ph[1], Pl[1], Ph[2], Pl[2], Ph[1], Pl[1],
                                               X, out, Ph[0], Pl[0], scal, 1, 1);

        // ---- sanitize + RESTART schedule ----
        san_pass1<<<2048, 256, 0, stream>>>(Ph[0], Pl[0], scal);        // fro2 -> scal[60]
        schedule2_kernel<<<1, 64, 0, stream>>>(scal);                   // inv, (a,b) tail
        san_pass2<<<2048, 256, 0, stream>>>(Ph[0], Pl[0], f0, scal);    // f0 = clean(Y2)/c~

        // ---- TAIL: 26 proven-fp32 iterations (fresh schedule) + final ----
        float* buf[3] = {f0, f1, out};
        int q = 0;
        for (int k = 0; k < NITER; ++k) {
            float* Y  = buf[q];
            float* T  = buf[(q + 1) % 3];
            float* Yn = buf[(q + 2) % 3];
            gemm_kernel<<<grid, blk, 0, stream>>>(Y, Y, T, nullptr, scal + 62, 0, 0, 0);
            gemm_kernel<<<grid, blk, 0, stream>>>(Y, T, Yn, Y, scal + 62, k, 1, 0);
            q = (q + 2) % 3;
        }
        // q == (0 + 52) % 3 == 1: S in f1 (no alias with out).
        // out = 0.5X + 0.5eps*I + 0.5(X-eps*I)*S
        gemm_kernel<<<grid, blk, 0, stream>>>(X, buf[q], out, X, scal, 0, 2, 1);
    } else {
        // ---------------- fp32 fallback (round-3 proven) ----------------
        float* ws0 = (float*)d_ws;
        float* ws1 = ws0 + NN;
        float* scal = ws1 + NN;

        hipMemsetAsync(scal, 0, 256 * sizeof(float), stream);
        fro_kernel<<<2048, 256, 0, stream>>>(X, scal);
        schedule_kernel<<<1, 64, 0, stream>>>(scal);
        init_kernel<<<2048, 256, 0, stream>>>(X, ws0, scal);

        float* buf[3] = {ws0, ws1, out};
        int p = 0;
        for (int k = 0; k < NITER; ++k) {
            float* Y  = buf[p];
            float* T  = buf[(p + 1) % 3];
            float* Yn = buf[(p + 2) % 3];
            gemm_kernel<<<grid, blk, 0, stream>>>(Y, Y, T, nullptr, scal, 0, 0, 0);
            gemm_kernel<<<grid, blk, 0, stream>>>(Y, T, Yn, Y, scal, k, 1, 0);
            p = (p + 2) % 3;
        }
        gemm_kernel<<<grid, blk, 0, stream>>>(X, buf[p], out, X, scal, 0, 2, 1);
    }
}